// Round 4
// baseline (357.665 us; speedup 1.0000x reference)
//
#include <hip/hip_runtime.h>

#define N_   512
#define V_   3889
#define V3   11667      // V_*3
#define J_   35
#define NB_  20
#define PF_K 306        // 34*9

__constant__ int c_parents[J_] = {0,0,1,2,3,4,5,6,7,8,9,6,11,12,13,6,15,16,17,18,
                                  16,20,21,22,23,16,25,26,27,28,29,30,16,1,1};

// ---------------- v_shaped = v_template + deform + beta @ shapedirs ----------
#define VS_G 4
__global__ __launch_bounds__(256) void k_vshaped(
    const float* __restrict__ beta, const float* __restrict__ deform,
    const float* __restrict__ vt,   const float* __restrict__ sd,
    float* __restrict__ VS) {
  int e  = blockIdx.x * 256 + threadIdx.x;   // element within a row (v*3+c)
  int n0 = blockIdx.y * VS_G;
  if (e >= V3) return;
  float base = vt[e];
  float acc[VS_G];
#pragma unroll
  for (int i = 0; i < VS_G; ++i) acc[i] = base + deform[(size_t)(n0 + i) * V3 + e];
#pragma unroll
  for (int b = 0; b < NB_; ++b) {
    float sv = sd[(size_t)b * V3 + e];
#pragma unroll
    for (int i = 0; i < VS_G; ++i) acc[i] += beta[(n0 + i) * NB_ + b] * sv;  // uniform -> s_load
  }
#pragma unroll
  for (int i = 0; i < VS_G; ++i) VS[(size_t)(n0 + i) * V3 + e] = acc[i];
}

// ------- Rodrigues: Rs (output) + pose_feature (pfT transposed [k][n]) ------
__global__ void k_rod(const float* __restrict__ theta,
                      float* __restrict__ Rs_out, float* __restrict__ pfT) {
  int i = blockIdx.x * blockDim.x + threadIdx.x;
  if (i >= N_ * J_) return;
  int n = i / J_, j = i % J_;
  const float* th = theta + n * (J_ * 3) + j * 3;
  float t0 = th[0], t1 = th[1], t2 = th[2];
  float angle = sqrtf(t0 * t0 + t1 * t1 + t2 * t2 + 1e-8f);
  float inv = 1.0f / angle;
  float r0 = t0 * inv, r1 = t1 * inv, r2 = t2 * inv;
  float s, c;
  sincosf(angle, &s, &c);
  float omc = 1.0f - c;
  float R[9];
  R[0] = c + omc * r0 * r0;      R[1] = omc * r0 * r1 - s * r2;  R[2] = omc * r0 * r2 + s * r1;
  R[3] = omc * r1 * r0 + s * r2; R[4] = c + omc * r1 * r1;       R[5] = omc * r1 * r2 - s * r0;
  R[6] = omc * r2 * r0 - s * r1; R[7] = omc * r2 * r1 + s * r0;  R[8] = c + omc * r2 * r2;
  float* ro = Rs_out + (size_t)n * (J_ * 9) + j * 9;
#pragma unroll
  for (int k = 0; k < 9; ++k) ro[k] = R[k];
  if (j > 0) {
#pragma unroll
    for (int k = 0; k < 9; ++k)
      pfT[(size_t)((j - 1) * 9 + k) * N_ + n] =
          R[k] - ((k == 0 || k == 4 || k == 8) ? 1.0f : 0.0f);
  }
}

// ------- transpose [V][J] -> [J][V] (used for Jr and for weights) -----------
__global__ __launch_bounds__(256) void k_trans_vj(
    const float* __restrict__ src, float* __restrict__ dst) {
  int idx = blockIdx.x * 256 + threadIdx.x;     // flat over dst (coalesced writes)
  if (idx >= V_ * J_) return;
  int j = idx / V_, v = idx % V_;
  dst[idx] = src[v * J_ + j];
}

// --------- dst[n,j,c] = sum_v src[n,v,c] * JrT[j,v] -------------------------
// one wave owns (1 n x 5 j); lanes stride v (coalesced). 3584 waves.
#define JRED_JG 5
#define JRED_GROUPS (J_ / JRED_JG)                 // 7
#define JRED_BLOCKS (N_ * JRED_GROUPS / 4)         // 896
__global__ __launch_bounds__(256) void k_jreduce3(
    const float* __restrict__ src, const float* __restrict__ JrT,
    float* __restrict__ dst) {
  int t = threadIdx.x;
  int lane = t & 63;
  int w = blockIdx.x * 4 + (t >> 6);
  int n  = w / JRED_GROUPS;
  int j0 = (w % JRED_GROUPS) * JRED_JG;
  const float* s0 = src + (size_t)n * V3;

  float acc[JRED_JG][3];
#pragma unroll
  for (int jj = 0; jj < JRED_JG; ++jj)
#pragma unroll
    for (int cc = 0; cc < 3; ++cc) acc[jj][cc] = 0.f;

  for (int iv = 0; iv < (V_ + 63) / 64; ++iv) {
    int v = iv * 64 + lane;
    bool ok = v < V_;
    float jr[JRED_JG];
#pragma unroll
    for (int jj = 0; jj < JRED_JG; ++jj)
      jr[jj] = ok ? JrT[(size_t)(j0 + jj) * V_ + v] : 0.f;
    float sx = ok ? s0[3 * v + 0] : 0.f;
    float sy = ok ? s0[3 * v + 1] : 0.f;
    float sz = ok ? s0[3 * v + 2] : 0.f;
#pragma unroll
    for (int jj = 0; jj < JRED_JG; ++jj) {
      acc[jj][0] += jr[jj] * sx;
      acc[jj][1] += jr[jj] * sy;
      acc[jj][2] += jr[jj] * sz;
    }
  }

#pragma unroll
  for (int jj = 0; jj < JRED_JG; ++jj)
#pragma unroll
    for (int cc = 0; cc < 3; ++cc) {
      float v = acc[jj][cc];
#pragma unroll
      for (int off = 32; off > 0; off >>= 1)
        v += __shfl_down(v, off, 64);
      acc[jj][cc] = v;
    }

  if (lane == 0) {
#pragma unroll
    for (int jj = 0; jj < JRED_JG; ++jj)
#pragma unroll
      for (int cc = 0; cc < 3; ++cc)
        dst[n * 105 + (j0 + jj) * 3 + cc] = acc[jj][cc];
  }
}

// ---------------- kinematic chain -> A[n][j][3][4] --------------------------
__global__ __launch_bounds__(256) void k_chain(
    const float* __restrict__ Rs, const float* __restrict__ Jp,
    const float* __restrict__ se, float* __restrict__ Aout) {
  __shared__ float loc[4][J_][12];
  __shared__ float res[4][J_][12];
  int t = threadIdx.x;
  int w = t >> 6, l = t & 63;
  int n = blockIdx.x * 4 + w;

  if (l < J_) {
    int j = l;
    const float* R = Rs + (size_t)n * (J_ * 9) + j * 9;
    float r[9];
#pragma unroll
    for (int k = 0; k < 9; ++k) r[k] = R[k];
    if (j == 0) {
#pragma unroll
      for (int rr = 0; rr < 3; ++rr) {
        loc[w][0][rr * 4 + 0] = r[rr * 3 + 0];
        loc[w][0][rr * 4 + 1] = r[rr * 3 + 1];
        loc[w][0][rr * 4 + 2] = r[rr * 3 + 2];
        loc[w][0][rr * 4 + 3] = Jp[n * 105 + rr];
      }
#pragma unroll
      for (int k = 0; k < 12; ++k) res[w][0][k] = loc[w][0][k];
    } else {
      int p = c_parents[j];
      float si[3], sp[3], jh[3];
#pragma unroll
      for (int cidx = 0; cidx < 3; ++cidx) {
        si[cidx] = se[n * 105 + j * 3 + cidx];
        sp[cidx] = se[n * 105 + p * 3 + cidx];
        jh[cidx] = Jp[n * 105 + j * 3 + cidx] - Jp[n * 105 + p * 3 + cidx];
      }
#pragma unroll
      for (int rr = 0; rr < 3; ++rr) {
        float invp = 1.0f / sp[rr];
        loc[w][j][rr * 4 + 0] = r[rr * 3 + 0] * si[0] * invp;
        loc[w][j][rr * 4 + 1] = r[rr * 3 + 1] * si[1] * invp;
        loc[w][j][rr * 4 + 2] = r[rr * 3 + 2] * si[2] * invp;
        loc[w][j][rr * 4 + 3] = jh[rr];
      }
    }
  }
  __syncthreads();

  for (int i = 1; i < J_; ++i) {
    if (l < 12) {
      int p = c_parents[i];
      int rr = l >> 2, cc = l & 3;
      float acc = (cc == 3) ? res[w][p][rr * 4 + 3] : 0.f;
#pragma unroll
      for (int k = 0; k < 3; ++k)
        acc += res[w][p][rr * 4 + k] * loc[w][i][k * 4 + cc];
      res[w][i][l] = acc;
    }
    __syncthreads();
  }

  if (l < J_) {
    int j = l;
    float jx = Jp[n * 105 + j * 3 + 0];
    float jy = Jp[n * 105 + j * 3 + 1];
    float jz = Jp[n * 105 + j * 3 + 2];
    float* Ao = Aout + (size_t)n * (J_ * 12) + j * 12;
#pragma unroll
    for (int rr = 0; rr < 3; ++rr) {
      float a0 = res[w][j][rr * 4 + 0];
      float a1 = res[w][j][rr * 4 + 1];
      float a2 = res[w][j][rr * 4 + 2];
      float a3 = res[w][j][rr * 4 + 3];
      Ao[rr * 4 + 0] = a0;
      Ao[rr * 4 + 1] = a1;
      Ao[rr * 4 + 2] = a2;
      Ao[rr * 4 + 3] = a3 - (a0 * jx + a1 * jy + a2 * jz);
    }
  }
}

// ----- v_posed += pose_feature @ posedirs (in place, pd staged via LDS) -----
// pd chunk [KC][256] in LDS: staging = 34 coalesced loads in flight/thread,
// one drain per chunk amortized over 34*32=1088 FMAs. pf via s_load broadcast.
#define VP_G 32
#define VP_KC 34   // 9 chunks * 34 = 306
__global__ __launch_bounds__(256) void k_vposed3(
    const float* __restrict__ pfT, const float* __restrict__ pd,
    float* __restrict__ VS) {
  __shared__ float pds[VP_KC][256];   // 34 KB
  int t = threadIdx.x;
  int e = blockIdx.x * 256 + t;
  bool ee = e < V3;
  int n0 = blockIdx.y * VP_G;
  float acc[VP_G];
#pragma unroll
  for (int i = 0; i < VP_G; ++i)
    acc[i] = ee ? VS[(size_t)(n0 + i) * V3 + e] : 0.f;

#pragma unroll 1
  for (int c = 0; c < PF_K / VP_KC; ++c) {
    int k0 = c * VP_KC;
    __syncthreads();
#pragma unroll
    for (int i = 0; i < VP_KC; ++i)
      pds[i][t] = ee ? pd[(size_t)(k0 + i) * V3 + e] : 0.f;
    __syncthreads();
#pragma unroll
    for (int i = 0; i < VP_KC; ++i) {
      float cur = pds[i][t];
      const float* pk = pfT + (size_t)(k0 + i) * N_ + n0;  // uniform -> s_load
#pragma unroll
      for (int nn = 0; nn < VP_G; ++nn) acc[nn] += pk[nn] * cur;
    }
  }
  if (ee) {
#pragma unroll
    for (int i = 0; i < VP_G; ++i) VS[(size_t)(n0 + i) * V3 + e] = acc[i];
  }
}

// ------ skinning: verts = (sum_j w*A) @ [v_posed,1] + trans -----------------
// A(n), trans(n) block-uniform -> s_loads; wtsT[j][v] -> 35 coalesced loads.
__global__ __launch_bounds__(256) void k_skin3(
    const float* __restrict__ Aw, const float* __restrict__ wtsT,
    const float* __restrict__ trans, float* __restrict__ VT) {
  int n = blockIdx.y;
  int v = blockIdx.x * 256 + threadIdx.x;
  if (v >= V_) return;
  const float* An = Aw + (size_t)n * (J_ * 12);   // uniform
  float T[12];
#pragma unroll
  for (int k = 0; k < 12; ++k) T[k] = 0.f;
#pragma unroll
  for (int j = 0; j < J_; ++j) {
    float wj = wtsT[(size_t)j * V_ + v];          // coalesced
#pragma unroll
    for (int k = 0; k < 12; ++k) T[k] += wj * An[j * 12 + k];
  }
  float* p = VT + (size_t)n * V3 + 3 * v;
  float x = p[0], y = p[1], z = p[2];
  float tx = trans[n * 3 + 0], ty = trans[n * 3 + 1], tz = trans[n * 3 + 2];
  p[0] = T[0] * x + T[1] * y + T[2]  * z + T[3]  + tx;
  p[1] = T[4] * x + T[5] * y + T[6]  * z + T[7]  + ty;
  p[2] = T[8] * x + T[9] * y + T[10] * z + T[11] + tz;
}

extern "C" void kernel_launch(void* const* d_in, const int* in_sizes, int n_in,
                              void* d_out, int out_size, void* d_ws, size_t ws_size,
                              hipStream_t stream) {
  const float* beta   = (const float*)d_in[0];
  const float* theta  = (const float*)d_in[1];
  const float* se     = (const float*)d_in[2];   // betas_extra (scales)
  const float* deform = (const float*)d_in[3];
  const float* trans  = (const float*)d_in[4];
  const float* vt     = (const float*)d_in[5];
  const float* sd     = (const float*)d_in[6];
  const float* pd     = (const float*)d_in[7];
  const float* Jr     = (const float*)d_in[8];
  const float* wts    = (const float*)d_in[9];

  float* out    = (float*)d_out;
  float* verts  = out;                               // N*V3 (also v_shaped/v_posed buffer)
  float* joints = out + (size_t)N_ * V3;             // N*105
  float* Rs     = joints + (size_t)N_ * 105;         // N*315

  float* ws = (float*)d_ws;
  float* pfT  = ws;                                  // PF_K*N = 156672
  float* Jp   = pfT + (size_t)PF_K * N_;             // N*105
  float* Aw   = Jp + (size_t)N_ * 105;               // N*420
  float* JrT  = Aw + (size_t)N_ * 420;               // J*V = 136115
  float* wtsT = JrT + (size_t)J_ * V_;               // J*V = 136115

  k_vshaped<<<dim3(46, N_ / VS_G), 256, 0, stream>>>(beta, deform, vt, sd, verts);
  k_trans_vj<<<(V_ * J_ + 255) / 256, 256, 0, stream>>>(Jr, JrT);
  k_trans_vj<<<(V_ * J_ + 255) / 256, 256, 0, stream>>>(wts, wtsT);
  k_rod<<<(N_ * J_ + 63) / 64, 64, 0, stream>>>(theta, Rs, pfT);
  k_jreduce3<<<JRED_BLOCKS, 256, 0, stream>>>(verts, JrT, Jp);
  k_chain<<<N_ / 4, 256, 0, stream>>>(Rs, Jp, se, Aw);
  k_vposed3<<<dim3(46, N_ / VP_G), 256, 0, stream>>>(pfT, pd, verts);
  k_skin3<<<dim3(16, N_), 256, 0, stream>>>(Aw, wtsT, trans, verts);
  k_jreduce3<<<JRED_BLOCKS, 256, 0, stream>>>(verts, JrT, joints);
}

// Round 5
// 274.876 us; speedup vs baseline: 1.3012x; 1.3012x over previous
//
#include <hip/hip_runtime.h>

#define N_   512
#define V_   3889
#define V3   11667      // V_*3
#define J_   35
#define NB_  20
#define PF_K 306        // 34*9
#define KP   320        // K padded to 10 MFMA k-steps of 32
#define KSTEPS 10
#define EP   11776      // 46*256, e padded

typedef __attribute__((ext_vector_type(8))) short short8;
typedef __attribute__((ext_vector_type(4))) float f32x4;

__constant__ int c_parents[J_] = {0,0,1,2,3,4,5,6,7,8,9,6,11,12,13,6,15,16,17,18,
                                  16,20,21,22,23,16,25,26,27,28,29,30,16,1,1};

static __device__ __forceinline__ unsigned short f2bf(float x) {
  union { float f; unsigned int u; } v; v.f = x;
  unsigned int r = v.u + 0x7FFF + ((v.u >> 16) & 1);   // round-to-nearest-even
  return (unsigned short)(r >> 16);
}

// ---------------- v_shaped = v_template + deform + beta @ shapedirs ----------
#define VS_G 4
__global__ __launch_bounds__(256) void k_vshaped(
    const float* __restrict__ beta, const float* __restrict__ deform,
    const float* __restrict__ vt,   const float* __restrict__ sd,
    float* __restrict__ VS) {
  int e  = blockIdx.x * 256 + threadIdx.x;
  int n0 = blockIdx.y * VS_G;
  if (e >= V3) return;
  float base = vt[e];
  float acc[VS_G];
#pragma unroll
  for (int i = 0; i < VS_G; ++i) acc[i] = base + deform[(size_t)(n0 + i) * V3 + e];
#pragma unroll
  for (int b = 0; b < NB_; ++b) {
    float sv = sd[(size_t)b * V3 + e];
#pragma unroll
    for (int i = 0; i < VS_G; ++i) acc[i] += beta[(n0 + i) * NB_ + b] * sv;
  }
#pragma unroll
  for (int i = 0; i < VS_G; ++i) VS[(size_t)(n0 + i) * V3 + e] = acc[i];
}

// ------- Rodrigues: Rs (fp32 out) + pose_feature in A-fragment bf16 layout --
// pfA layout: [mt=n>>4][ks=k>>5][q=(k>>3)&3][m=n&15][o=k&7]  (bf16)
__global__ void k_rod(const float* __restrict__ theta,
                      float* __restrict__ Rs_out, unsigned short* __restrict__ pfA) {
  int i = blockIdx.x * blockDim.x + threadIdx.x;
  if (i >= N_ * J_) return;
  int n = i / J_, j = i % J_;
  const float* th = theta + n * (J_ * 3) + j * 3;
  float t0 = th[0], t1 = th[1], t2 = th[2];
  float angle = sqrtf(t0 * t0 + t1 * t1 + t2 * t2 + 1e-8f);
  float inv = 1.0f / angle;
  float r0 = t0 * inv, r1 = t1 * inv, r2 = t2 * inv;
  float s, c;
  sincosf(angle, &s, &c);
  float omc = 1.0f - c;
  float R[9];
  R[0] = c + omc * r0 * r0;      R[1] = omc * r0 * r1 - s * r2;  R[2] = omc * r0 * r2 + s * r1;
  R[3] = omc * r1 * r0 + s * r2; R[4] = c + omc * r1 * r1;       R[5] = omc * r1 * r2 - s * r0;
  R[6] = omc * r2 * r0 - s * r1; R[7] = omc * r2 * r1 + s * r0;  R[8] = c + omc * r2 * r2;
  float* ro = Rs_out + (size_t)n * (J_ * 9) + j * 9;
#pragma unroll
  for (int k = 0; k < 9; ++k) ro[k] = R[k];
  if (j > 0) {
    int mt = n >> 4, m = n & 15;
#pragma unroll
    for (int kk = 0; kk < 9; ++kk) {
      int k = (j - 1) * 9 + kk;
      float v = R[kk] - ((kk == 0 || kk == 4 || kk == 8) ? 1.0f : 0.0f);
      size_t idx = ((((size_t)mt * KSTEPS + (k >> 5)) * 4 + ((k >> 3) & 3)) * 16 + m) * 8 + (k & 7);
      pfA[idx] = f2bf(v);
    }
  }
}

// ------- pd [K][V3] fp32 -> pdT [EP][KP] bf16 (transposed, zero-padded) -----
__global__ __launch_bounds__(256) void k_pd2bf(
    const float* __restrict__ pd, unsigned short* __restrict__ pdT) {
  int e  = blockIdx.x * 64 + (threadIdx.x & 63);
  int kg = threadIdx.x >> 6;             // 0..3 -> k-range [kg*80, +80)
  bool ev = e < V3;
  for (int kk = 0; kk < 80; kk += 8) {
    int k0 = kg * 80 + kk;
    union { unsigned short u[8]; short8 s; } pk;
#pragma unroll
    for (int ii = 0; ii < 8; ++ii) {
      int k = k0 + ii;
      float x = (ev && k < PF_K) ? pd[(size_t)k * V3 + e] : 0.f;
      pk.u[ii] = f2bf(x);
    }
    *(short8*)(pdT + (size_t)e * KP + k0) = pk.s;
  }
}

// ------- transpose [V][J] -> [J][V] (used for Jr and for weights) -----------
__global__ __launch_bounds__(256) void k_trans_vj(
    const float* __restrict__ src, float* __restrict__ dst) {
  int idx = blockIdx.x * 256 + threadIdx.x;
  if (idx >= V_ * J_) return;
  int j = idx / V_, v = idx % V_;
  dst[idx] = src[v * J_ + j];
}

// --------- dst[n,j,c] = sum_v src[n,v,c] * JrT[j,v] -------------------------
#define JRED_JG 5
#define JRED_GROUPS (J_ / JRED_JG)                 // 7
#define JRED_BLOCKS (N_ * JRED_GROUPS / 4)         // 896
__global__ __launch_bounds__(256) void k_jreduce3(
    const float* __restrict__ src, const float* __restrict__ JrT,
    float* __restrict__ dst) {
  int t = threadIdx.x;
  int lane = t & 63;
  int w = blockIdx.x * 4 + (t >> 6);
  int n  = w / JRED_GROUPS;
  int j0 = (w % JRED_GROUPS) * JRED_JG;
  const float* s0 = src + (size_t)n * V3;

  float acc[JRED_JG][3];
#pragma unroll
  for (int jj = 0; jj < JRED_JG; ++jj)
#pragma unroll
    for (int cc = 0; cc < 3; ++cc) acc[jj][cc] = 0.f;

  for (int iv = 0; iv < (V_ + 63) / 64; ++iv) {
    int v = iv * 64 + lane;
    bool ok = v < V_;
    float jr[JRED_JG];
#pragma unroll
    for (int jj = 0; jj < JRED_JG; ++jj)
      jr[jj] = ok ? JrT[(size_t)(j0 + jj) * V_ + v] : 0.f;
    float sx = ok ? s0[3 * v + 0] : 0.f;
    float sy = ok ? s0[3 * v + 1] : 0.f;
    float sz = ok ? s0[3 * v + 2] : 0.f;
#pragma unroll
    for (int jj = 0; jj < JRED_JG; ++jj) {
      acc[jj][0] += jr[jj] * sx;
      acc[jj][1] += jr[jj] * sy;
      acc[jj][2] += jr[jj] * sz;
    }
  }

#pragma unroll
  for (int jj = 0; jj < JRED_JG; ++jj)
#pragma unroll
    for (int cc = 0; cc < 3; ++cc) {
      float v = acc[jj][cc];
#pragma unroll
      for (int off = 32; off > 0; off >>= 1)
        v += __shfl_down(v, off, 64);
      acc[jj][cc] = v;
    }

  if (lane == 0) {
#pragma unroll
    for (int jj = 0; jj < JRED_JG; ++jj)
#pragma unroll
      for (int cc = 0; cc < 3; ++cc)
        dst[n * 105 + (j0 + jj) * 3 + cc] = acc[jj][cc];
  }
}

// ---------------- kinematic chain -> A[n][j][3][4] --------------------------
__global__ __launch_bounds__(256) void k_chain(
    const float* __restrict__ Rs, const float* __restrict__ Jp,
    const float* __restrict__ se, float* __restrict__ Aout) {
  __shared__ float loc[4][J_][12];
  __shared__ float res[4][J_][12];
  int t = threadIdx.x;
  int w = t >> 6, l = t & 63;
  int n = blockIdx.x * 4 + w;

  if (l < J_) {
    int j = l;
    const float* R = Rs + (size_t)n * (J_ * 9) + j * 9;
    float r[9];
#pragma unroll
    for (int k = 0; k < 9; ++k) r[k] = R[k];
    if (j == 0) {
#pragma unroll
      for (int rr = 0; rr < 3; ++rr) {
        loc[w][0][rr * 4 + 0] = r[rr * 3 + 0];
        loc[w][0][rr * 4 + 1] = r[rr * 3 + 1];
        loc[w][0][rr * 4 + 2] = r[rr * 3 + 2];
        loc[w][0][rr * 4 + 3] = Jp[n * 105 + rr];
      }
#pragma unroll
      for (int k = 0; k < 12; ++k) res[w][0][k] = loc[w][0][k];
    } else {
      int p = c_parents[j];
      float si[3], sp[3], jh[3];
#pragma unroll
      for (int cidx = 0; cidx < 3; ++cidx) {
        si[cidx] = se[n * 105 + j * 3 + cidx];
        sp[cidx] = se[n * 105 + p * 3 + cidx];
        jh[cidx] = Jp[n * 105 + j * 3 + cidx] - Jp[n * 105 + p * 3 + cidx];
      }
#pragma unroll
      for (int rr = 0; rr < 3; ++rr) {
        float invp = 1.0f / sp[rr];
        loc[w][j][rr * 4 + 0] = r[rr * 3 + 0] * si[0] * invp;
        loc[w][j][rr * 4 + 1] = r[rr * 3 + 1] * si[1] * invp;
        loc[w][j][rr * 4 + 2] = r[rr * 3 + 2] * si[2] * invp;
        loc[w][j][rr * 4 + 3] = jh[rr];
      }
    }
  }
  __syncthreads();

  for (int i = 1; i < J_; ++i) {
    if (l < 12) {
      int p = c_parents[i];
      int rr = l >> 2, cc = l & 3;
      float acc = (cc == 3) ? res[w][p][rr * 4 + 3] : 0.f;
#pragma unroll
      for (int k = 0; k < 3; ++k)
        acc += res[w][p][rr * 4 + k] * loc[w][i][k * 4 + cc];
      res[w][i][l] = acc;
    }
    __syncthreads();
  }

  if (l < J_) {
    int j = l;
    float jx = Jp[n * 105 + j * 3 + 0];
    float jy = Jp[n * 105 + j * 3 + 1];
    float jz = Jp[n * 105 + j * 3 + 2];
    float* Ao = Aout + (size_t)n * (J_ * 12) + j * 12;
#pragma unroll
    for (int rr = 0; rr < 3; ++rr) {
      float a0 = res[w][j][rr * 4 + 0];
      float a1 = res[w][j][rr * 4 + 1];
      float a2 = res[w][j][rr * 4 + 2];
      float a3 = res[w][j][rr * 4 + 3];
      Ao[rr * 4 + 0] = a0;
      Ao[rr * 4 + 1] = a1;
      Ao[rr * 4 + 2] = a2;
      Ao[rr * 4 + 3] = a3 - (a0 * jx + a1 * jy + a2 * jz);
    }
  }
}

// ----- v_posed += pf @ pd via bf16 MFMA (no LDS, no barriers) ---------------
// block: 4 waves; tile M=32 (2 mt), N=256e (wave owns 64e = 4 et).
// A frag: pfA[mt][ks][q][m=lane&15][8] -> wave load = 1KB contiguous.
// B frag: pdT[e][k]: lane reads 16B at e=etile+col, k=ks*32+q*8.
// C/D: col=lane&15 (e), row=q*4+reg (n within tile)  [m89 layout]
__global__ __launch_bounds__(256) void k_vposed_mfma(
    const unsigned short* __restrict__ pfA, const unsigned short* __restrict__ pdT,
    float* __restrict__ VS) {
  int t = threadIdx.x;
  int wv = t >> 6, lane = t & 63;
  int q = lane >> 4, col = lane & 15;
  int mtg0 = blockIdx.y * 2;             // global m-tile base (n = mt*16+..)
  int ebase = blockIdx.x * 256 + wv * 64;

  const short8* Ap = (const short8*)pfA;
  const short8* Bp = (const short8*)pdT;

  f32x4 acc[2][4];
#pragma unroll
  for (int mt = 0; mt < 2; ++mt)
#pragma unroll
    for (int et = 0; et < 4; ++et) acc[mt][et] = (f32x4){0.f, 0.f, 0.f, 0.f};

#pragma unroll 2
  for (int ks = 0; ks < KSTEPS; ++ks) {
    short8 a[2];
#pragma unroll
    for (int mt = 0; mt < 2; ++mt)
      a[mt] = Ap[(((mtg0 + mt) * KSTEPS + ks) * 4 + q) * 16 + col];
    short8 b[4];
#pragma unroll
    for (int et = 0; et < 4; ++et)
      b[et] = Bp[(size_t)(ebase + et * 16 + col) * (KP / 8) + ks * 4 + q];
#pragma unroll
    for (int mt = 0; mt < 2; ++mt)
#pragma unroll
      for (int et = 0; et < 4; ++et)
        acc[mt][et] = __builtin_amdgcn_mfma_f32_16x16x32_bf16(a[mt], b[et], acc[mt][et], 0, 0, 0);
  }

#pragma unroll
  for (int mt = 0; mt < 2; ++mt) {
#pragma unroll
    for (int et = 0; et < 4; ++et) {
      int e = ebase + et * 16 + col;
      if (e < V3) {
#pragma unroll
        for (int r = 0; r < 4; ++r) {
          int n = (mtg0 + mt) * 16 + q * 4 + r;
          size_t off = (size_t)n * V3 + e;
          VS[off] += acc[mt][et][r];
        }
      }
    }
  }
}

// ------ skinning: verts = (sum_j w*A) @ [v_posed,1] + trans -----------------
__global__ __launch_bounds__(256) void k_skin3(
    const float* __restrict__ Aw, const float* __restrict__ wtsT,
    const float* __restrict__ trans, float* __restrict__ VT) {
  int n = blockIdx.y;
  int v = blockIdx.x * 256 + threadIdx.x;
  if (v >= V_) return;
  const float* An = Aw + (size_t)n * (J_ * 12);   // uniform
  float T[12];
#pragma unroll
  for (int k = 0; k < 12; ++k) T[k] = 0.f;
#pragma unroll
  for (int j = 0; j < J_; ++j) {
    float wj = wtsT[(size_t)j * V_ + v];          // coalesced
#pragma unroll
    for (int k = 0; k < 12; ++k) T[k] += wj * An[j * 12 + k];
  }
  float* p = VT + (size_t)n * V3 + 3 * v;
  float x = p[0], y = p[1], z = p[2];
  float tx = trans[n * 3 + 0], ty = trans[n * 3 + 1], tz = trans[n * 3 + 2];
  p[0] = T[0] * x + T[1] * y + T[2]  * z + T[3]  + tx;
  p[1] = T[4] * x + T[5] * y + T[6]  * z + T[7]  + ty;
  p[2] = T[8] * x + T[9] * y + T[10] * z + T[11] + tz;
}

extern "C" void kernel_launch(void* const* d_in, const int* in_sizes, int n_in,
                              void* d_out, int out_size, void* d_ws, size_t ws_size,
                              hipStream_t stream) {
  const float* beta   = (const float*)d_in[0];
  const float* theta  = (const float*)d_in[1];
  const float* se     = (const float*)d_in[2];
  const float* deform = (const float*)d_in[3];
  const float* trans  = (const float*)d_in[4];
  const float* vt     = (const float*)d_in[5];
  const float* sd     = (const float*)d_in[6];
  const float* pd     = (const float*)d_in[7];
  const float* Jr     = (const float*)d_in[8];
  const float* wts    = (const float*)d_in[9];

  float* out    = (float*)d_out;
  float* verts  = out;                               // N*V3 (v_shaped/v_posed buffer)
  float* joints = out + (size_t)N_ * V3;             // N*105
  float* Rs     = joints + (size_t)N_ * 105;         // N*315

  char* w = (char*)d_ws;
  unsigned short* pdT = (unsigned short*)w;                      // EP*KP*2   = 7,536,640 B
  unsigned short* pfA = (unsigned short*)(w + 7536640);          // 512*320*2 =   327,680 B
  float* Jp   = (float*)(w + 7864320);                           // 512*105*4 =   215,040 B
  float* Aw   = (float*)(w + 8079360);                           // 512*420*4 =   860,160 B
  float* JrT  = (float*)(w + 8939520);                           // 136115*4  =   544,460 B
  float* wtsT = (float*)(w + 9484032);                           // 136115*4

  hipMemsetAsync(pfA, 0, (size_t)N_ * KP * 2, stream);           // zero k-pad

  k_vshaped<<<dim3(46, N_ / VS_G), 256, 0, stream>>>(beta, deform, vt, sd, verts);
  k_trans_vj<<<(V_ * J_ + 255) / 256, 256, 0, stream>>>(Jr, JrT);
  k_trans_vj<<<(V_ * J_ + 255) / 256, 256, 0, stream>>>(wts, wtsT);
  k_pd2bf<<<EP / 64, 256, 0, stream>>>(pd, pdT);
  k_rod<<<(N_ * J_ + 63) / 64, 64, 0, stream>>>(theta, Rs, pfA);
  k_jreduce3<<<JRED_BLOCKS, 256, 0, stream>>>(verts, JrT, Jp);
  k_chain<<<N_ / 4, 256, 0, stream>>>(Rs, Jp, se, Aw);
  k_vposed_mfma<<<dim3(46, N_ / 32), 256, 0, stream>>>(pfA, pdT, verts);
  k_skin3<<<dim3(16, N_), 256, 0, stream>>>(Aw, wtsT, trans, verts);
  k_jreduce3<<<JRED_BLOCKS, 256, 0, stream>>>(verts, JrT, joints);
}